// Round 13
// baseline (65.789 us; speedup 1.0000x reference)
//
#include <hip/hip_runtime.h>

#define N_PIX 4096
#define N_CH 256
#define KSEL 16
#define SCAP 64

__device__ __forceinline__ unsigned f2key(float f) {
  unsigned u = __float_as_uint(f);
  return u ^ ((unsigned)((int)u >> 31) | 0x80000000u);
}
__device__ __forceinline__ float key2f(unsigned k) {
  unsigned u = (k & 0x80000000u) ? (k ^ 0x80000000u) : ~k;
  return __uint_as_float(u);
}
__device__ __forceinline__ unsigned umax2(unsigned a, unsigned b) { return a > b ? a : b; }

// feat [B, C, N] -> feat_t [B, N, C], 32x32 LDS tile transpose
__global__ void transpose_feat_kernel(const float* __restrict__ feat,
                                      float* __restrict__ feat_t) {
  __shared__ float tile[32][33];
  const int b = blockIdx.z;
  const int n0 = blockIdx.x * 32;
  const int c0 = blockIdx.y * 32;
  const int tx = threadIdx.x, ty = threadIdx.y;
  const float* src = feat + (size_t)b * N_CH * N_PIX;
  float* dst = feat_t + (size_t)b * N_PIX * N_CH;
#pragma unroll
  for (int j = 0; j < 32; j += 8)
    tile[ty + j][tx] = src[(size_t)(c0 + ty + j) * N_PIX + n0 + tx];
  __syncthreads();
#pragma unroll
  for (int j = 0; j < 32; j += 8)
    dst[(size_t)(n0 + ty + j) * N_CH + c0 + tx] = tile[tx][ty + j];
}

// Block = 4 waves; each wave owns TWO rows (A,B) processed phase-interleaved:
// every long-latency wait (row-batch loads, candidate refetch, gathers) is
// issued in pairs, and every serial VALU chain (T1 radix, extraction, stage-2
// radix) exists twice as independent straight-line code the scheduler can
// interleave. Selection per row == R12's proven path. One barrier (staging).
template <bool FT>
__global__ __launch_bounds__(256, 3) void topk_dual_kernel(
    const float* __restrict__ aff, const float* __restrict__ feat,
    float* __restrict__ out) {
  __shared__ unsigned s_slab[4][2][SCAP];  // candidate indices, ~0 = pad
  __shared__ uint2 s_wj[4][2][KSEL];       // (exp(v-vref) bits, idx)
  __shared__ float s_out[8][N_CH];

  const int tid = threadIdx.x;
  const int lane = tid & 63;
  const int w = tid >> 6;
  // bijective chunked XCD swizzle (1024 = 8*128): consecutive rg share an XCD
  const int bid = blockIdx.x;
  const int rg = (bid & 7) * 128 + (bid >> 3);
  const int b = rg >> 9;               // 512 row-groups per batch
  const int i0 = (rg & 511) * 8;       // 8 consecutive i per block
  const int rowA = rg * 8 + 2 * w;
  const int rowB = rowA + 1;
  const unsigned long long lt = (1ull << lane) - 1ull;

  const float* arowA_f = aff + (size_t)rowA * N_PIX;
  const float* arowB_f = aff + (size_t)rowB * N_PIX;
  const float4* arowA = (const float4*)arowA_f;
  const float4* arowB = (const float4*)arowB_f;

  unsigned* const slabA = s_slab[w][0];
  unsigned* const slabB = s_slab[w][1];
  uint2* const wjA = s_wj[w][0];
  uint2* const wjB = s_wj[w][1];

  // ---- rolling loads + hi-16 pack for both rows ----
  unsigned phA[32], phB[32];
  unsigned mA = 0, mB = 0;
  float4 bA[4], bB[4];
#pragma unroll
  for (int r = 0; r < 4; ++r) bA[r] = arowA[r * 64 + lane];
#pragma unroll
  for (int r = 0; r < 4; ++r) bB[r] = arowB[r * 64 + lane];
#pragma unroll
  for (int bq = 0; bq < 4; ++bq) {
    // pack A batch bq
#pragma unroll
    for (int r = 0; r < 4; ++r) {
      const int q = bq * 4 + r;
      const float4 v = bA[r];
      const unsigned k0 = f2key(v.x), k1 = f2key(v.y);
      const unsigned k2 = f2key(v.z), k3 = f2key(v.w);
      mA = umax2(mA, umax2(umax2(k0, k1), umax2(k2, k3)));
      phA[2 * q + 0] = (k1 & 0xFFFF0000u) | (k0 >> 16);
      phA[2 * q + 1] = (k3 & 0xFFFF0000u) | (k2 >> 16);
    }
    if (bq < 3) {
#pragma unroll
      for (int r = 0; r < 4; ++r) bA[r] = arowA[((bq + 1) * 4 + r) * 64 + lane];
    }
    // pack B batch bq
#pragma unroll
    for (int r = 0; r < 4; ++r) {
      const int q = bq * 4 + r;
      const float4 v = bB[r];
      const unsigned k0 = f2key(v.x), k1 = f2key(v.y);
      const unsigned k2 = f2key(v.z), k3 = f2key(v.w);
      mB = umax2(mB, umax2(umax2(k0, k1), umax2(k2, k3)));
      phB[2 * q + 0] = (k1 & 0xFFFF0000u) | (k0 >> 16);
      phB[2 * q + 1] = (k3 & 0xFFFF0000u) | (k2 >> 16);
    }
    if (bq < 3) {
#pragma unroll
      for (int r = 0; r < 4; ++r) bB[r] = arowB[((bq + 1) * 4 + r) * 64 + lane];
    }
  }

  // ---- T1 radix for A and B, interleaved branchless 16-step chains ----
  const unsigned tA = mA >> 16, tB = mB >> 16;
  unsigned p1A = 0, need1A = KSEL, p1B = 0, need1B = KSEL;
#pragma unroll
  for (int bit = 15; bit >= 0; --bit) {
    const unsigned wantA = (p1A << 1) | 1u;
    const unsigned cntA = (unsigned)__popcll(__ballot((tA >> bit) == wantA));
    const unsigned wantB = (p1B << 1) | 1u;
    const unsigned cntB = (unsigned)__popcll(__ballot((tB >> bit) == wantB));
    const bool takeA = cntA >= need1A;
    p1A = wantA - (takeA ? 0u : 1u);
    need1A = takeA ? need1A : need1A - cntA;
    const bool takeB = cntB >= need1B;
    p1B = wantB - (takeB ? 0u : 1u);
    need1B = takeB ? need1B : need1B - cntB;
  }
  const unsigned T1A = p1A, T1B = p1B;

  slabA[lane] = 0xFFFFFFFFu;
  slabB[lane] = 0xFFFFFFFFu;

  // ---- extraction into named regs (branch-free cndmask chains), A then B ----
  unsigned clA = 0, a0 = 0, a1 = 0, a2 = 0, a3 = 0;
#pragma unroll
  for (int p = 0; p < 32; ++p) {
    const unsigned lo = phA[p] & 0xFFFFu, hi = phA[p] >> 16;
    const unsigned jlo = (unsigned)((p >> 1) * 256 + lane * 4 + (p & 1) * 2);
    if (lo >= T1A) {
      a3 = (clA == 3) ? jlo : a3; a2 = (clA == 2) ? jlo : a2;
      a1 = (clA == 1) ? jlo : a1; a0 = (clA == 0) ? jlo : a0;
      ++clA;
    }
    if (hi >= T1A) {
      const unsigned jhi = jlo + 1;
      a3 = (clA == 3) ? jhi : a3; a2 = (clA == 2) ? jhi : a2;
      a1 = (clA == 1) ? jhi : a1; a0 = (clA == 0) ? jhi : a0;
      ++clA;
    }
  }
  unsigned clB = 0, b0r = 0, b1r = 0, b2r = 0, b3r = 0;
#pragma unroll
  for (int p = 0; p < 32; ++p) {
    const unsigned lo = phB[p] & 0xFFFFu, hi = phB[p] >> 16;
    const unsigned jlo = (unsigned)((p >> 1) * 256 + lane * 4 + (p & 1) * 2);
    if (lo >= T1B) {
      b3r = (clB == 3) ? jlo : b3r; b2r = (clB == 2) ? jlo : b2r;
      b1r = (clB == 1) ? jlo : b1r; b0r = (clB == 0) ? jlo : b0r;
      ++clB;
    }
    if (hi >= T1B) {
      const unsigned jhi = jlo + 1;
      b3r = (clB == 3) ? jhi : b3r; b2r = (clB == 2) ? jhi : b2r;
      b1r = (clB == 1) ? jhi : b1r; b0r = (clB == 0) ? jhi : b0r;
      ++clB;
    }
  }

  // ---- 3-ballot prefix compaction (A then B), with parachutes ----
  unsigned totalA, totalB;
  if (__builtin_expect(__ballot(clA > 4) == 0ull, 1)) {
    const unsigned long long c0m = __ballot(clA & 1u);
    const unsigned long long c1m = __ballot(clA & 2u);
    const unsigned long long c2m = __ballot(clA & 4u);
    const unsigned start = (unsigned)__popcll(c0m & lt) +
                           2u * (unsigned)__popcll(c1m & lt) +
                           4u * (unsigned)__popcll(c2m & lt);
    totalA = (unsigned)__popcll(c0m) + 2u * (unsigned)__popcll(c1m) +
             4u * (unsigned)__popcll(c2m);
    if (clA > 0 && start + 0 < SCAP) slabA[start + 0] = a0;
    if (clA > 1 && start + 1 < SCAP) slabA[start + 1] = a1;
    if (clA > 2 && start + 2 < SCAP) slabA[start + 2] = a2;
    if (clA > 3 && start + 3 < SCAP) slabA[start + 3] = a3;
  } else {  // rare lane-overflow: ballot-rank extraction from packed regs
    unsigned base = 0;
#pragma unroll
    for (int p = 0; p < 32; ++p) {
      const unsigned lo = phA[p] & 0xFFFFu, hi = phA[p] >> 16;
      const unsigned jlo = (unsigned)((p >> 1) * 256 + lane * 4 + (p & 1) * 2);
      {
        const bool sel = lo >= T1A;
        const unsigned long long mk = __ballot(sel);
        if (sel) {
          const unsigned pos = base + (unsigned)__popcll(mk & lt);
          if (pos < SCAP) slabA[pos] = jlo;
        }
        base += (unsigned)__popcll(mk);
      }
      {
        const bool sel = hi >= T1A;
        const unsigned long long mk = __ballot(sel);
        if (sel) {
          const unsigned pos = base + (unsigned)__popcll(mk & lt);
          if (pos < SCAP) slabA[pos] = jlo + 1;
        }
        base += (unsigned)__popcll(mk);
      }
    }
    totalA = base;
  }
  if (__builtin_expect(__ballot(clB > 4) == 0ull, 1)) {
    const unsigned long long c0m = __ballot(clB & 1u);
    const unsigned long long c1m = __ballot(clB & 2u);
    const unsigned long long c2m = __ballot(clB & 4u);
    const unsigned start = (unsigned)__popcll(c0m & lt) +
                           2u * (unsigned)__popcll(c1m & lt) +
                           4u * (unsigned)__popcll(c2m & lt);
    totalB = (unsigned)__popcll(c0m) + 2u * (unsigned)__popcll(c1m) +
             4u * (unsigned)__popcll(c2m);
    if (clB > 0 && start + 0 < SCAP) slabB[start + 0] = b0r;
    if (clB > 1 && start + 1 < SCAP) slabB[start + 1] = b1r;
    if (clB > 2 && start + 2 < SCAP) slabB[start + 2] = b2r;
    if (clB > 3 && start + 3 < SCAP) slabB[start + 3] = b3r;
  } else {
    unsigned base = 0;
#pragma unroll
    for (int p = 0; p < 32; ++p) {
      const unsigned lo = phB[p] & 0xFFFFu, hi = phB[p] >> 16;
      const unsigned jlo = (unsigned)((p >> 1) * 256 + lane * 4 + (p & 1) * 2);
      {
        const bool sel = lo >= T1B;
        const unsigned long long mk = __ballot(sel);
        if (sel) {
          const unsigned pos = base + (unsigned)__popcll(mk & lt);
          if (pos < SCAP) slabB[pos] = jlo;
        }
        base += (unsigned)__popcll(mk);
      }
      {
        const bool sel = hi >= T1B;
        const unsigned long long mk = __ballot(sel);
        if (sel) {
          const unsigned pos = base + (unsigned)__popcll(mk & lt);
          if (pos < SCAP) slabB[pos] = jlo + 1;
        }
        base += (unsigned)__popcll(mk);
      }
    }
    totalB = base;
  }

  // ---- stage 2 for both rows: refetch (2 loads in flight) + radix pair ----
  const bool okA = totalA <= SCAP, okB = totalB <= SCAP;
  if (__builtin_expect(okA && okB, 1)) {
    const unsigned jjA = slabA[lane];
    const unsigned jjB = slabB[lane];
    const bool validA = jjA != 0xFFFFFFFFu;
    const bool validB = jjB != 0xFFFFFFFFu;
    const float fvalA = arowA_f[validA ? jjA : 0u];
    const float fvalB = arowB_f[validB ? jjB : 0u];
    const unsigned cvA = validA ? f2key(fvalA) : 0u;
    const unsigned cvB = validB ? f2key(fvalB) : 0u;
    const unsigned cjA = validA ? jjA : 0xFFFFFFFFu;
    const unsigned cjB = validB ? jjB : 0xFFFFFFFFu;

    unsigned p2A = 0, need2A = KSEL, p2B = 0, need2B = KSEL;
#pragma unroll
    for (int bit = 31; bit >= 0; --bit) {
      const unsigned wantA = (p2A << 1) | 1u;
      const unsigned cntA = (unsigned)__popcll(__ballot((cvA >> bit) == wantA));
      const unsigned wantB = (p2B << 1) | 1u;
      const unsigned cntB = (unsigned)__popcll(__ballot((cvB >> bit) == wantB));
      const bool takeA = cntA >= need2A;
      p2A = wantA - (takeA ? 0u : 1u);
      need2A = takeA ? need2A : need2A - cntA;
      const bool takeB = cntB >= need2B;
      p2B = wantB - (takeB ? 0u : 1u);
      need2B = takeB ? need2B : need2B - cntB;
    }
    // winners: > T2 always in; ==T2 ties: need2 of them by lowest index
    bool winA = cvA > p2A, winB = cvB > p2B;
    const bool eqA = validA && (cvA == p2A);
    const bool eqB = validB && (cvB == p2B);
    const unsigned cntEqA = (unsigned)__popcll(__ballot(eqA));
    const unsigned cntEqB = (unsigned)__popcll(__ballot(eqB));
    if (__builtin_expect(cntEqA == need2A, 1)) {
      winA = winA || eqA;
    } else {  // cold: duplicate float values at the threshold
      bool tq = eqA;
      for (unsigned q = 0; q < need2A; ++q) {
        unsigned mi = tq ? cjA : 0xFFFFFFFFu;
#pragma unroll
        for (int off = 32; off; off >>= 1) {
          const unsigned o = (unsigned)__shfl_xor((int)mi, off, 64);
          mi = o < mi ? o : mi;
        }
        if (tq && cjA == mi) { winA = true; tq = false; }
      }
    }
    if (__builtin_expect(cntEqB == need2B, 1)) {
      winB = winB || eqB;
    } else {
      bool tq = eqB;
      for (unsigned q = 0; q < need2B; ++q) {
        unsigned mi = tq ? cjB : 0xFFFFFFFFu;
#pragma unroll
        for (int off = 32; off; off >>= 1) {
          const unsigned o = (unsigned)__shfl_xor((int)mi, off, 64);
          mi = o < mi ? o : mi;
        }
        if (tq && cjB == mi) { winB = true; tq = false; }
      }
    }
    const unsigned long long wmA = __ballot(winA);
    const unsigned long long wmB = __ballot(winB);
    if (winA)
      wjA[(unsigned)__popcll(wmA & lt)] =
          make_uint2(__float_as_uint(__expf(key2f(cvA) - key2f(p2A))), cjA);
    if (winB)
      wjB[(unsigned)__popcll(wmB & lt)] =
          make_uint2(__float_as_uint(__expf(key2f(cvB) - key2f(p2B))), cjB);
  } else {
    // ---- ultra-cold slab overflow: streaming exact radix per affected row ----
#pragma unroll
    for (int rr = 0; rr < 2; ++rr) {
      const bool bad = rr == 0 ? !okA : !okB;
      if (!bad) continue;
      const float* arf = rr == 0 ? arowA_f : arowB_f;
      const float4* ar4 = rr == 0 ? arowA : arowB;
      uint2* wj = rr == 0 ? wjA : wjB;
      unsigned p2 = 0, need2 = KSEL;
      for (int bit = 31; bit >= 0; --bit) {
        const unsigned want = (p2 << 1) | 1u;
        unsigned cnt = 0;
        for (int q = 0; q < 16; ++q) {
          float4 v = ar4[q * 64 + lane];
          cnt += (unsigned)__popcll(__ballot((f2key(v.x) >> bit) == want));
          cnt += (unsigned)__popcll(__ballot((f2key(v.y) >> bit) == want));
          cnt += (unsigned)__popcll(__ballot((f2key(v.z) >> bit) == want));
          cnt += (unsigned)__popcll(__ballot((f2key(v.w) >> bit) == want));
        }
        const bool take = cnt >= need2;
        p2 = want - (take ? 0u : 1u);
        need2 = take ? need2 : need2 - cnt;
      }
      const float vref = key2f(p2);
      unsigned rk = 0;
      for (int q = 0; q < 16; ++q) {
        float4 v = ar4[q * 64 + lane];
        const float fvv[4] = {v.x, v.y, v.z, v.w};
        for (int c = 0; c < 4; ++c) {
          const unsigned kk = f2key(fvv[c]);
          const bool sel = kk > p2;
          const unsigned long long mk = __ballot(sel);
          if (sel) {
            const unsigned pos = rk + (unsigned)__popcll(mk & lt);
            if (pos < KSEL)
              wj[pos] = make_uint2(__float_as_uint(__expf(fvv[c] - vref)),
                                   (unsigned)(q * 256 + lane * 4 + c));
          }
          rk += (unsigned)__popcll(mk);
        }
      }
      unsigned jprev = 0xFFFFFFFFu;
      for (unsigned tq = rk; tq < KSEL; ++tq) {
        unsigned mi = 0xFFFFFFFFu;
        for (int q = 0; q < 16; ++q) {
          float4 v = ar4[q * 64 + lane];
          const float fvv[4] = {v.x, v.y, v.z, v.w};
          for (int c = 0; c < 4; ++c) {
            const unsigned j = (unsigned)(q * 256 + lane * 4 + c);
            if (f2key(fvv[c]) == p2 && (jprev == 0xFFFFFFFFu || j > jprev) &&
                j < mi)
              mi = j;
          }
        }
#pragma unroll
        for (int off = 32; off; off >>= 1) {
          const unsigned o = (unsigned)__shfl_xor((int)mi, off, 64);
          mi = o < mi ? o : mi;
        }
        if (lane == 0) wj[tq] = make_uint2(__float_as_uint(1.0f), mi);
        jprev = mi;
      }
      (void)arf;
    }
  }

  // ---- gathers for A and B interleaved; deferred softmax; staged stores ----
  float ssumA = 0.f, ssumB = 0.f;
  float axA = 0.f, ayA = 0.f, azA = 0.f, awA = 0.f;
  float axB = 0.f, ayB = 0.f, azB = 0.f, awB = 0.f;
  if (FT) {
    const float* fb = feat + (size_t)b * N_PIX * N_CH + lane * 4;  // [B,N,C]
#pragma unroll
    for (int k = 0; k < KSEL; ++k) {
      const uint2 ttA = wjA[k];
      const uint2 ttB = wjB[k];
      const float ewA = __uint_as_float(ttA.x);
      const float ewB = __uint_as_float(ttB.x);
      ssumA += ewA; ssumB += ewB;
      const float4 fA = *(const float4*)(fb + (size_t)ttA.y * N_CH);
      const float4 fB = *(const float4*)(fb + (size_t)ttB.y * N_CH);
      axA += ewA * fA.x; ayA += ewA * fA.y; azA += ewA * fA.z; awA += ewA * fA.w;
      axB += ewB * fB.x; ayB += ewB * fB.y; azB += ewB * fB.z; awB += ewB * fB.w;
    }
  } else {
    const float* fb = feat + (size_t)b * N_CH * N_PIX;  // [B,C,N] fallback
    const int c0s = lane * 4;
#pragma unroll
    for (int k = 0; k < KSEL; ++k) {
      const uint2 ttA = wjA[k];
      const uint2 ttB = wjB[k];
      const float ewA = __uint_as_float(ttA.x);
      const float ewB = __uint_as_float(ttB.x);
      ssumA += ewA; ssumB += ewB;
#pragma unroll
      for (int c = 0; c < 4; ++c) {
        const float vA = fb[(size_t)(c0s + c) * N_PIX + ttA.y];
        const float vB = fb[(size_t)(c0s + c) * N_PIX + ttB.y];
        if (c == 0) { axA += ewA * vA; axB += ewB * vB; }
        if (c == 1) { ayA += ewA * vA; ayB += ewB * vB; }
        if (c == 2) { azA += ewA * vA; azB += ewB * vB; }
        if (c == 3) { awA += ewA * vA; awB += ewB * vB; }
      }
    }
  }
  const float invA = 1.0f / ssumA;
  const float invB = 1.0f / ssumB;
  float4 oA, oB;
  oA.x = axA * invA; oA.y = ayA * invA; oA.z = azA * invA; oA.w = awA * invA;
  oB.x = axB * invB; oB.y = ayB * invB; oB.z = azB * invB; oB.w = awB * invB;
  *(float4*)&s_out[2 * w + 0][lane * 4] = oA;
  *(float4*)&s_out[2 * w + 1][lane * 4] = oB;

  __syncthreads();  // the only block barrier: full 32B-per-channel assembly

  {
    const int c = tid;
    float4 o1, o2;
    o1.x = s_out[0][c]; o1.y = s_out[1][c]; o1.z = s_out[2][c]; o1.w = s_out[3][c];
    o2.x = s_out[4][c]; o2.y = s_out[5][c]; o2.z = s_out[6][c]; o2.w = s_out[7][c];
    float* op = out + ((size_t)(b * N_CH + c)) * N_PIX + i0;
    *(float4*)op = o1;
    *(float4*)(op + 4) = o2;
  }
}

extern "C" void kernel_launch(void* const* d_in, const int* in_sizes, int n_in,
                              void* d_out, int out_size, void* d_ws, size_t ws_size,
                              hipStream_t stream) {
  const float* aff = (const float*)d_in[0];
  const float* feat = (const float*)d_in[1];
  float* out = (float*)d_out;
  const size_t feat_t_bytes = (size_t)2 * N_PIX * N_CH * sizeof(float);
  if (ws_size >= feat_t_bytes) {
    float* feat_t = (float*)d_ws;
    dim3 tb(32, 8, 1);
    dim3 tg(N_PIX / 32, N_CH / 32, 2);
    transpose_feat_kernel<<<tg, tb, 0, stream>>>(feat, feat_t);
    topk_dual_kernel<true><<<1024, 256, 0, stream>>>(aff, feat_t, out);
  } else {
    topk_dual_kernel<false><<<1024, 256, 0, stream>>>(aff, feat, out);
  }
}